// Round 10
// baseline (31.948 us; speedup 1.0000x reference)
//
#include <hip/hip_runtime.h>
#include <hip/hip_bf16.h>

#define D_MODEL 256
#define D_K 128

typedef short bf16x8 __attribute__((ext_vector_type(8)));
typedef float f32x4 __attribute__((ext_vector_type(4)));

__device__ inline unsigned short f2bf(float x) {
    union { float f; unsigned u; } v; v.f = x;
    unsigned r = v.u + 0x7FFFu + ((v.u >> 16) & 1u);  // RNE (finite inputs)
    return (unsigned short)(r >> 16);
}
__device__ inline float bf2f(unsigned short h) {
    union { unsigned u; float f; } v; v.u = ((unsigned)h) << 16; return v.f;
}

// ================ kernel 1: dense QKV GEMM (bf16 MFMA) + segment boundary scan ================
// grid = n/64 GEMM blocks + ceil(n/256) scan blocks, 256 threads.
// GEMM block: 64 rows x 384 cols (Q|K|V). W staged fp32->bf16 in LDS per 32-k tile.
// LDS: As[64][40] bf16 (5,120 B) + Ws[384][40] bf16 (30,720 B) = 35,840 B.
__global__ __launch_bounds__(256, 1) void qkv_gemm(
    const float* __restrict__ A,
    const float* __restrict__ Wq, const float* __restrict__ bq,
    const float* __restrict__ Wk, const float* __restrict__ bk,
    const float* __restrict__ Wv, const float* __restrict__ bv,
    const int* __restrict__ midx,
    unsigned short* __restrict__ Qg, unsigned short* __restrict__ Kg,
    unsigned short* __restrict__ Vg, int* __restrict__ Seg, int n, int nmol)
{
    const int tid = threadIdx.x, blk = blockIdx.x;
    const int nrb = n >> 6;

    if (blk >= nrb) {
        // parallel boundary detection on sorted midx
        const int gid = (blk - nrb) * 256 + tid;
        if (gid < n) {
            // int64 detection: sorted int64 high words are 0 -> last int32 slot == 0
            const int stride = (midx[n - 1] == 0) ? 2 : 1;
            const int v = midx[(size_t)gid * stride];
            const int prev = (gid == 0) ? -1 : midx[(size_t)(gid - 1) * stride];
            for (int u = prev + 1; u <= v; ++u) Seg[u] = gid;
            if (gid == n - 1)
                for (int u = v + 1; u <= nmol; ++u) Seg[u] = n;
        }
        return;
    }

    __shared__ unsigned short As[64 * 40];
    __shared__ unsigned short Ws[384 * 40];
    const int wave = tid >> 6, lane = tid & 63;
    const int lr = lane & 15, g = lane >> 4;
    const int r0 = blk * 64;

    f32x4 acc[24];
    #pragma unroll
    for (int i = 0; i < 24; ++i) acc[i] = {0.f, 0.f, 0.f, 0.f};

    for (int k0 = 0; k0 < D_MODEL; k0 += 32) {
        // stage A-tile 64x32 fp32->bf16: 2048 elems = 2 iters x 256 thr x 4 elems
        // (round-9 bug: l<8 overran the tile -> OOB global reads + LDS corruption)
        #pragma unroll
        for (int l = 0; l < 2; ++l) {
            int elem = (tid + l * 256) * 4;
            int r = elem >> 5, c = elem & 31;
            float4 a = *(const float4*)&A[(size_t)(r0 + r) * D_MODEL + k0 + c];
            unsigned short o[4] = {f2bf(a.x), f2bf(a.y), f2bf(a.z), f2bf(a.w)};
            *(unsigned long long*)&As[r * 40 + c] = *(const unsigned long long*)o;
        }
        // stage W-tile 32k x 384c transposed into Ws[c][k]:
        // task = (kb, c); 8 k-strided global reads per task are lane-coalesced (consecutive c),
        // LDS write is one contiguous 16B store (no transpose conflicts).
        #pragma unroll
        for (int l = 0; l < 6; ++l) {
            int task = tid + l * 256;            // 1536 tasks = 4 kb x 384 c
            int c = task % 384, kb = task / 384;
            int which = c >> 7, cc = c & 127;
            const float* W = which == 0 ? Wq : (which == 1 ? Wk : Wv);
            unsigned short t8[8];
            #pragma unroll
            for (int u = 0; u < 8; ++u)
                t8[u] = f2bf(W[(size_t)(k0 + kb * 8 + u) * D_K + cc]);
            *(uint4*)&Ws[c * 40 + kb * 8] = *(const uint4*)t8;
        }
        __syncthreads();

        // wave w owns rows w*16..+16; 24 col-tiles
        bf16x8 af = *(const bf16x8*)&As[(wave * 16 + lr) * 40 + g * 8];
        #pragma unroll
        for (int ct = 0; ct < 24; ++ct) {
            bf16x8 wf = *(const bf16x8*)&Ws[(ct * 16 + lr) * 40 + g * 8];
            acc[ct] = __builtin_amdgcn_mfma_f32_16x16x32_bf16(af, wf, acc[ct], 0, 0, 0);
        }
        __syncthreads();
    }

    // epilogue: +bias, Q scaled by 1/sqrt(128), store bf16 row-major [n][128] per matrix
    const float qs = 0.08838834764831845f;
    #pragma unroll
    for (int ct = 0; ct < 24; ++ct) {
        int which = ct >> 3, colg = (ct & 7) * 16 + lr;
        const float* bias = which == 0 ? bq : (which == 1 ? bk : bv);
        unsigned short* dst = which == 0 ? Qg : (which == 1 ? Kg : Vg);
        float sc = (which == 0) ? qs : 1.f;
        float bb = bias[colg];
        #pragma unroll
        for (int r = 0; r < 4; ++r) {
            int grow = r0 + wave * 16 + g * 4 + r;   // C/D: row=(lane>>4)*4+r, col=lane&15
            dst[(size_t)grow * D_K + colg] = f2bf((acc[ct][r] + bb) * sc);
        }
    }
}

// ================ kernel 2: per-molecule attention + pooling (reads bf16 Q/K/V) ================
// LDS (6,400 B): S[48][52] bf16 @0; rinv @4992; csum @5184; emb f32[2][128] @5376.
template<int NRT>
__device__ __forceinline__ void attn_fast(
    const unsigned short* __restrict__ Qg, const unsigned short* __restrict__ Kg,
    const unsigned short* __restrict__ Vg, float* __restrict__ out,
    unsigned char* lds, int s, int m, int mol, int n)
{
    unsigned short* S = (unsigned short*)lds;
    float* rinv = (float*)(lds + 4992);
    float* csum = (float*)(lds + 5184);
    float* emb  = (float*)(lds + 5376);

    const int tid = threadIdx.x;
    const int wave = tid >> 6, lane = tid & 63;
    const int lr = lane & 15, g = lane >> 4;

    // ---- scores via MFMA, fragments straight from global bf16 Q/K ----
    for (int job = wave; job < NRT * NRT; job += 4) {
        int ti = job / NRT, tj = job % NRT;
        int qrow = s + ti * 16 + lr; if (qrow > n - 1) qrow = n - 1;  // clamp; masked below
        int krow = s + tj * 16 + lr; if (krow > n - 1) krow = n - 1;
        const unsigned short* qp = Qg + (size_t)qrow * D_K + g * 8;
        const unsigned short* kp = Kg + (size_t)krow * D_K + g * 8;
        f32x4 sa = {0.f, 0.f, 0.f, 0.f};
        #pragma unroll
        for (int kk = 0; kk < 4; ++kk) {
            bf16x8 qf = *(const bf16x8*)(qp + kk * 32);
            bf16x8 kf = *(const bf16x8*)(kp + kk * 32);
            sa = __builtin_amdgcn_mfma_f32_16x16x32_bf16(qf, kf, sa, 0, 0, 0);
        }
        int jcol = tj * 16 + lr, ibase = ti * 16 + g * 4;
        #pragma unroll
        for (int r = 0; r < 4; ++r)
            S[(ibase + r) * 52 + jcol] = f2bf(sa[r]);
    }
    __syncthreads();

    // ---- row softmax: 4 lanes per row ----
    {
        int row = tid >> 2, sub = tid & 3;
        if (row < m) {
            float mx = -3.4e38f;
            for (int j = sub; j < m; j += 4) mx = fmaxf(mx, bf2f(S[row * 52 + j]));
            mx = fmaxf(mx, __shfl_xor(mx, 1));
            mx = fmaxf(mx, __shfl_xor(mx, 2));
            float sum = 0.f;
            for (int j = sub; j < m; j += 4) {
                float ev = __expf(bf2f(S[row * 52 + j]) - mx);
                S[row * 52 + j] = f2bf(ev);
                sum += ev;
            }
            sum += __shfl_xor(sum, 1);
            sum += __shfl_xor(sum, 2);
            if (sub == 0) rinv[row] = 1.f / sum;
        }
    }
    __syncthreads();

    // ---- column sums of normalized weights ----
    {
        int col = tid >> 2, sub = tid & 3;
        if (col < m) {
            float a = 0.f;
            for (int i = sub; i < m; i += 4) a += bf2f(S[i * 52 + col]) * rinv[i];
            a += __shfl_xor(a, 1);
            a += __shfl_xor(a, 2);
            if (sub == 0) csum[col] = a;
        }
    }
    __syncthreads();

    // ---- emb[d] = sum_j csum[j] * V[s+j][d] (coalesced 256B row reads) ----
    {
        int d = tid & 127, h = tid >> 7;
        float a = 0.f;
        for (int j = h; j < m; j += 2) a += csum[j] * bf2f(Vg[(size_t)(s + j) * D_K + d]);
        emb[h * D_K + d] = a;
        __syncthreads();
        if (tid < D_K) out[(size_t)mol * D_K + tid] = emb[tid] + emb[D_K + tid];
    }
}

__global__ __launch_bounds__(256) void attn_pool(
    const unsigned short* __restrict__ Qg, const unsigned short* __restrict__ Kg,
    const unsigned short* __restrict__ Vg, const int* __restrict__ Seg,
    float* __restrict__ out, float* __restrict__ ML, int n)
{
    __shared__ __align__(16) unsigned char lds[6400];
    const int tid = threadIdx.x, mol = blockIdx.x;
    const int s = Seg[mol], e = Seg[mol + 1];
    const int m = e - s;

    if (m == 0) {
        if (tid < D_K) out[(size_t)mol * D_K + tid] = 0.f;
        return;
    }
    if (m <= 16) { attn_fast<1>(Qg, Kg, Vg, out, lds, s, m, mol, n); return; }
    if (m <= 32) { attn_fast<2>(Qg, Kg, Vg, out, lds, s, m, mol, n); return; }
    if (m <= 48) { attn_fast<3>(Qg, Kg, Vg, out, lds, s, m, mol, n); return; }

    // ---- slow fallback (m > 48, statistically never): streaming two-phase ----
    float* embS = (float*)lds;
    if (tid < D_K) embS[tid] = 0.f;
    __syncthreads();
    float* Mv = ML;
    float* Lv = ML + n;

    for (int i = tid; i < m; i += 256) {
        const unsigned short* q = Qg + (size_t)(s + i) * D_K;
        float mx = -3.4e38f, sum = 0.f;
        for (int j = 0; j < m; ++j) {
            const unsigned short* k = Kg + (size_t)(s + j) * D_K;
            float sc = 0.f;
            for (int t = 0; t < D_K; ++t) sc += bf2f(q[t]) * bf2f(k[t]);
            if (sc > mx) { sum = sum * __expf(mx - sc) + 1.f; mx = sc; }
            else         { sum += __expf(sc - mx); }
        }
        Mv[s + i] = mx;
        Lv[s + i] = 1.f / sum;
    }
    __threadfence_block();
    __syncthreads();

    for (int j = tid; j < m; j += 256) {
        const unsigned short* k = Kg + (size_t)(s + j) * D_K;
        float cj = 0.f;
        for (int i = 0; i < m; ++i) {
            const unsigned short* q = Qg + (size_t)(s + i) * D_K;
            float sc = 0.f;
            for (int t = 0; t < D_K; ++t) sc += bf2f(q[t]) * bf2f(k[t]);
            cj += __expf(sc - Mv[s + i]) * Lv[s + i];
        }
        const unsigned short* v = Vg + (size_t)(s + j) * D_K;
        for (int d = 0; d < D_K; ++d) atomicAdd(&embS[d], cj * bf2f(v[d]));
    }
    __syncthreads();
    if (tid < D_K) out[(size_t)mol * D_K + tid] = embS[tid];
}

extern "C" void kernel_launch(void* const* d_in, const int* in_sizes, int n_in,
                              void* d_out, int out_size, void* d_ws, size_t ws_size,
                              hipStream_t stream) {
    const float* frag = (const float*)d_in[0];
    const int*   midx = (const int*)d_in[1];
    const float* Wq = (const float*)d_in[2];
    const float* bq = (const float*)d_in[3];
    const float* Wk = (const float*)d_in[4];
    const float* bk = (const float*)d_in[5];
    const float* Wv = (const float*)d_in[6];
    const float* bv = (const float*)d_in[7];
    float* out = (float*)d_out;

    const int n = in_sizes[1];          // 8192
    const int nmol = out_size / D_K;    // 512

    unsigned short* Qg = (unsigned short*)d_ws;
    unsigned short* Kg = Qg + (size_t)n * D_K;
    unsigned short* Vg = Kg + (size_t)n * D_K;
    int* Seg = (int*)(Vg + (size_t)n * D_K);
    float* ML = (float*)(Seg + ((nmol + 1 + 3) & ~3));   // 16B-aligned, 2*n floats

    const int nrb = n >> 6;                              // 128
    const int scanBlocks = (n + 255) / 256;              // 32

    qkv_gemm<<<nrb + scanBlocks, 256, 0, stream>>>(frag, Wq, bq, Wk, bk, Wv, bv, midx,
                                                   Qg, Kg, Vg, Seg, n, nmol);
    attn_pool<<<nmol, 256, 0, stream>>>(Qg, Kg, Vg, Seg, out, ML, n);
}

// Round 11
// 19.804 us; speedup vs baseline: 1.6132x; 1.6132x over previous
//
#include <hip/hip_runtime.h>
#include <hip/hip_bf16.h>

#define D_MODEL 256
#define D_K 128
#define CH 48       // slow-path staging chunk rows; also max fast-path rows (NRT=3)

typedef short bf16x8 __attribute__((ext_vector_type(8)));
typedef float f32x4 __attribute__((ext_vector_type(4)));

__device__ inline unsigned short f2bf(float x) {
    union { float f; unsigned u; } v; v.f = x;
    unsigned r = v.u + 0x7FFFu + ((v.u >> 16) & 1u);  // RNE (finite inputs)
    return (unsigned short)(r >> 16);
}
__device__ inline float bf2f(unsigned short h) {
    union { unsigned u; float f; } v; v.u = ((unsigned)h) << 16; return v.f;
}

// ---- LDS layout (bytes). Total 57,088 -> 2 blocks/CU ----
// At  [48][256] bf16, XOR-swizzled rows (bits 4-6)     : [0, 24576)
// Vb  [48][136] bf16 (aliases At after QKV barrier)    : [0, 13056)
// Qb  [48][136] bf16                                   : [24576, 37632)
// Kb  [48][136] bf16                                   : [37632, 50688)
// S   [48][52]  bf16                                   : [50688, 55680)
// rinv f32[48] (first 2 slots: s,e ints during search) : [55680, 55872)
// csum f32[48]                                         : [55872, 56064)
// emb  f32[2][128]                                     : [56064, 57088)
#define AT_BYTE(r, c2) (((r) << 9) + ((((c2) << 1)) ^ (((r) & 7) << 4)))

// wave-cooperative lower bound on sorted p (stride in int32 slots): smallest i with p[i] >= val.
// All 64 lanes of the calling wave participate. guess = starting estimate.
__device__ __forceinline__ int wave_lb(const int* __restrict__ p, int stride, int n, int val, int guess) {
    const int lane = threadIdx.x & 63;
    int base = guess - 32;
    while (true) {
        int idx = base + lane;
        int v;
        if (idx < 0)        v = -2147483647 - 1;
        else if (idx >= n)  v = 2147483647;
        else                v = p[(size_t)idx * stride];
        unsigned long long ge = __ballot(v >= val);
        if (ge == 0ULL) { base += 64; continue; }            // boundary right of window
        int v0 = __shfl(v, 0);
        if (v0 >= val && base > 0) { base -= 63; continue; } // boundary at/left of base (overlap 1 -> no cycle)
        return base + (__ffsll((unsigned long long)ge) - 1);
    }
}

// build B-operand fragment for output column cc at k-window k0 from fp32 W (transpose + convert on the fly)
__device__ __forceinline__ bf16x8 w_frag(const float* __restrict__ W, int cc, int k0, int g) {
    const float* p = W + (size_t)(k0 + g * 8) * D_K + cc;
    unsigned short t8[8];
    #pragma unroll
    for (int j = 0; j < 8; ++j) t8[j] = f2bf(p[(size_t)j * D_K]);
    return *(const bf16x8*)t8;
}

// QKV tile pass: At(LDS) x W(global fp32) -> acc[6][NRT]
// ct = wave + cl*4 covers 24 col-tiles (Q 0-7, K 8-15, V 16-23), rt covers NRT row-tiles.
template<int NRT>
__device__ __forceinline__ void qkv_tiles(
    const unsigned char* lds,
    const float* __restrict__ Wq, const float* __restrict__ Wk, const float* __restrict__ Wv,
    int wave, int lr, int g, f32x4 (&acc)[6][NRT])
{
    #pragma unroll
    for (int cl = 0; cl < 6; ++cl) {
        const int ct = wave + cl * 4;
        const int which = ct >> 3, cc = (ct & 7) * 16 + lr;
        const float* W = which == 0 ? Wq : (which == 1 ? Wk : Wv);
        #pragma unroll
        for (int k0 = 0; k0 < 8; ++k0) {
            bf16x8 bf = w_frag(W, cc, k0 * 32, g);
            #pragma unroll
            for (int rt = 0; rt < NRT; ++rt) {
                bf16x8 af = *(const bf16x8*)(lds + AT_BYTE(rt * 16 + lr, k0 * 32 + g * 8));
                acc[cl][rt] = __builtin_amdgcn_mfma_f32_16x16x32_bf16(af, bf, acc[cl][rt], 0, 0, 0);
            }
        }
    }
}

// ---------------- fast path (m <= NRT*16): R7 structure, W direct from fp32 ----------------
template<int NRT>
__device__ __forceinline__ void fast_path(
    const float* __restrict__ A,
    const float* __restrict__ Wq, const float* __restrict__ bq,
    const float* __restrict__ Wk, const float* __restrict__ bk,
    const float* __restrict__ Wv, const float* __restrict__ bv,
    float* __restrict__ out, unsigned char* lds, int s, int m, int mol)
{
    unsigned short* Qb = (unsigned short*)(lds + 24576);
    unsigned short* Kb = (unsigned short*)(lds + 37632);
    unsigned short* Vb = (unsigned short*)(lds);        // aliases At (after barrier)
    unsigned short* S  = (unsigned short*)(lds + 50688);
    float* rinv = (float*)(lds + 55680);
    float* csum = (float*)(lds + 55872);
    float* emb  = (float*)(lds + 56064);

    const int tid = threadIdx.x;
    const int wave = tid >> 6, lane = tid & 63;
    const int lr = lane & 15, g = lane >> 4;

    // ---- stage A rows -> At bf16 (coalesced, zero-pad to NRT*16 rows) ----
    #pragma unroll
    for (int it = 0; it < NRT * 4; ++it) {
        int eidx = tid * 4 + it * 1024;
        int r = eidx >> 8, c = eidx & 255;
        float4 a;
        if (r < m) a = *(const float4*)&A[(size_t)(s + r) * D_MODEL + c];
        else       a = make_float4(0.f, 0.f, 0.f, 0.f);
        unsigned short o[4] = {f2bf(a.x), f2bf(a.y), f2bf(a.z), f2bf(a.w)};
        *(unsigned long long*)(lds + AT_BYTE(r, c)) = *(const unsigned long long*)o;
    }
    __syncthreads();

    // ---- QKV MFMA ----
    f32x4 acc[6][NRT];
    #pragma unroll
    for (int i = 0; i < 6; ++i)
        #pragma unroll
        for (int j = 0; j < NRT; ++j) acc[i][j] = {0.f, 0.f, 0.f, 0.f};
    qkv_tiles<NRT>(lds, Wq, Wk, Wv, wave, lr, g, acc);
    __syncthreads();   // all At reads done; Vb may overwrite

    // ---- write Q,K,V (+bias, Q scaled) to LDS bf16 ----
    const float qs = 0.08838834764831845f; // 1/sqrt(128)
    #pragma unroll
    for (int cl = 0; cl < 6; ++cl) {
        int ct = wave + cl * 4;
        int which = ct >> 3;
        int col = (ct & 7) * 16 + lr;
        const float* bsrc = which == 0 ? bq : (which == 1 ? bk : bv);
        float bb = bsrc[col];
        float sc = which == 0 ? qs : 1.f;
        unsigned short* dst = which == 0 ? Qb : (which == 1 ? Kb : Vb);
        #pragma unroll
        for (int rt = 0; rt < NRT; ++rt) {
            int rbase = rt * 16 + g * 4;
            #pragma unroll
            for (int r = 0; r < 4; ++r)
                dst[(rbase + r) * 136 + col] = f2bf((acc[cl][rt][r] + bb) * sc);
        }
    }
    __syncthreads();

    // ---- scores via MFMA: S[i][j] = Q_i . K_j ----
    for (int job = wave; job < NRT * NRT; job += 4) {
        int ti = job / NRT, tj = job % NRT;
        f32x4 sa = {0.f, 0.f, 0.f, 0.f};
        #pragma unroll
        for (int kk = 0; kk < 4; ++kk) {
            bf16x8 qf = *(const bf16x8*)&Qb[(ti * 16 + lr) * 136 + kk * 32 + g * 8];
            bf16x8 kf = *(const bf16x8*)&Kb[(tj * 16 + lr) * 136 + kk * 32 + g * 8];
            sa = __builtin_amdgcn_mfma_f32_16x16x32_bf16(qf, kf, sa, 0, 0, 0);
        }
        int jcol = tj * 16 + lr, ibase = ti * 16 + g * 4;
        #pragma unroll
        for (int r = 0; r < 4; ++r)
            S[(ibase + r) * 52 + jcol] = f2bf(sa[r]);
    }
    __syncthreads();

    // ---- row softmax: 4 lanes per row ----
    {
        int row = tid >> 2, sub = tid & 3;
        if (row < m) {
            float mx = -3.4e38f;
            for (int j = sub; j < m; j += 4) mx = fmaxf(mx, bf2f(S[row * 52 + j]));
            mx = fmaxf(mx, __shfl_xor(mx, 1));
            mx = fmaxf(mx, __shfl_xor(mx, 2));
            float sum = 0.f;
            for (int j = sub; j < m; j += 4) {
                float ev = __expf(bf2f(S[row * 52 + j]) - mx);
                S[row * 52 + j] = f2bf(ev);
                sum += ev;
            }
            sum += __shfl_xor(sum, 1);
            sum += __shfl_xor(sum, 2);
            if (sub == 0) rinv[row] = 1.f / sum;
        }
    }
    __syncthreads();

    // ---- column sums of normalized weights ----
    {
        int col = tid >> 2, sub = tid & 3;
        if (col < m) {
            float a = 0.f;
            for (int i = sub; i < m; i += 4) a += bf2f(S[i * 52 + col]) * rinv[i];
            a += __shfl_xor(a, 1);
            a += __shfl_xor(a, 2);
            if (sub == 0) csum[col] = a;
        }
    }
    __syncthreads();

    // ---- emb[d] = sum_j csum[j] * V[j][d] ----
    {
        int d = tid & 127, h = tid >> 7;
        float a = 0.f;
        for (int j = h; j < m; j += 2) a += csum[j] * bf2f(Vb[j * 136 + d]);
        emb[h * D_K + d] = a;
        __syncthreads();
        if (tid < D_K) out[(size_t)mol * D_K + tid] = emb[tid] + emb[D_K + tid];
    }
}

// ---------------- single kernel: per-molecule everything (no prep, no second node) ----------------
__global__ __launch_bounds__(256, 2) void fused_one(
    const float* __restrict__ A,
    const float* __restrict__ Wq, const float* __restrict__ bq,
    const float* __restrict__ Wk, const float* __restrict__ bk,
    const float* __restrict__ Wv, const float* __restrict__ bv,
    const int* __restrict__ midx,
    float* __restrict__ out,
    float* __restrict__ Qw, float* __restrict__ Kw, float* __restrict__ Vw,
    float* __restrict__ ML, int n, int nmol)
{
    __shared__ __align__(16) unsigned char lds[57088];
    int* se = (int*)(lds + 55680);   // temp: [0]=s, [1]=e (rinv area, reused later)

    const int tid = threadIdx.x, mol = blockIdx.x;
    const int wave = tid >> 6;

    // int64 detection: sorted int64 high words are 0 -> last int32 slot == 0
    const int stride = (midx[n - 1] == 0) ? 2 : 1;

    // ---- segment bounds: waves 0 and 1 search concurrently ----
    if (wave == 0) {
        int s_ = wave_lb(midx, stride, n, mol, (int)(((long long)mol * n) / nmol));
        if ((tid & 63) == 0) se[0] = s_;
    } else if (wave == 1) {
        int e_ = wave_lb(midx, stride, n, mol + 1, (int)(((long long)(mol + 1) * n) / nmol));
        if ((tid & 63) == 0) se[1] = e_;
    }
    __syncthreads();
    const int s = se[0], e = se[1];
    const int m = e - s;
    __syncthreads();   // se consumed; rinv area free for reuse

    if (m == 0) {
        if (tid < D_K) out[(size_t)mol * D_K + tid] = 0.f;
        return;
    }
    if (m <= 16) { fast_path<1>(A, Wq, bq, Wk, bk, Wv, bv, out, lds, s, m, mol); return; }
    if (m <= 32) { fast_path<2>(A, Wq, bq, Wk, bk, Wv, bv, out, lds, s, m, mol); return; }
    if (m <= 48) { fast_path<3>(A, Wq, bq, Wk, bk, Wv, bv, out, lds, s, m, mol); return; }

    // ================= slow fallback (m > 48): chunked QKV to global, then streaming =================
    const int lane = tid & 63;
    const int lr = lane & 15, g = lane >> 4;
    const float qs = 0.08838834764831845f;
    float* emb = (float*)(lds + 56064);

    for (int r0 = 0; r0 < m; r0 += CH) {
        #pragma unroll
        for (int it = 0; it < (CH * 256) / 1024; ++it) {
            int eidx = tid * 4 + it * 1024;
            int r = eidx >> 8, c = eidx & 255;
            float4 a;
            if (r0 + r < m) a = *(const float4*)&A[(size_t)(s + r0 + r) * D_MODEL + c];
            else            a = make_float4(0.f, 0.f, 0.f, 0.f);
            unsigned short o[4] = {f2bf(a.x), f2bf(a.y), f2bf(a.z), f2bf(a.w)};
            *(unsigned long long*)(lds + AT_BYTE(r, c)) = *(const unsigned long long*)o;
        }
        __syncthreads();

        f32x4 acc[6][3];
        #pragma unroll
        for (int i = 0; i < 6; ++i)
            #pragma unroll
            for (int j = 0; j < 3; ++j) acc[i][j] = {0.f, 0.f, 0.f, 0.f};
        qkv_tiles<3>(lds, Wq, Wk, Wv, wave, lr, g, acc);

        #pragma unroll
        for (int cl = 0; cl < 6; ++cl) {
            int ct = wave + cl * 4;
            int which = ct >> 3;
            int col = (ct & 7) * 16 + lr;
            const float* bsrc = which == 0 ? bq : (which == 1 ? bk : bv);
            float bb = bsrc[col];
            float sc = which == 0 ? qs : 1.f;
            float* dst = which == 0 ? Qw : (which == 1 ? Kw : Vw);
            #pragma unroll
            for (int rt = 0; rt < 3; ++rt) {
                int rbase = rt * 16 + g * 4;
                #pragma unroll
                for (int r = 0; r < 4; ++r) {
                    int lrow = rbase + r;
                    if (r0 + lrow < m)
                        dst[(size_t)(s + r0 + lrow) * D_K + col] = (acc[cl][rt][r] + bb) * sc;
                }
            }
        }
        __syncthreads();
    }

    if (tid < D_K) emb[tid] = 0.f;
    float* Mv = ML;
    float* Lv = ML + n;
    __threadfence();
    __syncthreads();

    for (int i = tid; i < m; i += 256) {
        const float4* q = (const float4*)(Qw + (size_t)(s + i) * D_K);
        float mx = -3.4e38f, sum = 0.f;
        for (int j = 0; j < m; ++j) {
            const float4* k = (const float4*)(Kw + (size_t)(s + j) * D_K);
            float sc = 0.f;
            #pragma unroll
            for (int t = 0; t < D_K / 4; ++t) {
                float4 a = q[t], b = k[t];
                sc += a.x * b.x + a.y * b.y + a.z * b.z + a.w * b.w;
            }
            if (sc > mx) { sum = sum * __expf(mx - sc) + 1.f; mx = sc; }
            else         { sum += __expf(sc - mx); }
        }
        Mv[s + i] = mx;
        Lv[s + i] = 1.f / sum;
    }
    __threadfence();
    __syncthreads();

    for (int j = tid; j < m; j += 256) {
        const float4* k = (const float4*)(Kw + (size_t)(s + j) * D_K);
        float cj = 0.f;
        for (int i = 0; i < m; ++i) {
            const float4* q = (const float4*)(Qw + (size_t)(s + i) * D_K);
            float sc = 0.f;
            #pragma unroll
            for (int t = 0; t < D_K / 4; ++t) {
                float4 a = q[t], b = k[t];
                sc += a.x * b.x + a.y * b.y + a.z * b.z + a.w * b.w;
            }
            cj += __expf(sc - Mv[s + i]) * Lv[s + i];
        }
        const float* v = Vw + (size_t)(s + j) * D_K;
        for (int d = 0; d < D_K; ++d) atomicAdd(&emb[d], cj * v[d]);
    }
    __syncthreads();
    if (tid < D_K) out[(size_t)mol * D_K + tid] = emb[tid];
}

extern "C" void kernel_launch(void* const* d_in, const int* in_sizes, int n_in,
                              void* d_out, int out_size, void* d_ws, size_t ws_size,
                              hipStream_t stream) {
    const float* frag = (const float*)d_in[0];
    const int*   midx = (const int*)d_in[1];
    const float* Wq = (const float*)d_in[2];
    const float* bq = (const float*)d_in[3];
    const float* Wk = (const float*)d_in[4];
    const float* bk = (const float*)d_in[5];
    const float* Wv = (const float*)d_in[6];
    const float* bv = (const float*)d_in[7];
    float* out = (float*)d_out;

    const int n = in_sizes[1];          // 8192
    const int nmol = out_size / D_K;    // 512

    float* Qw = (float*)d_ws;           // slow-path scratch only
    float* Kw = Qw + (size_t)n * D_K;
    float* Vw = Kw + (size_t)n * D_K;
    float* ML = Vw + (size_t)n * D_K;   // 2*n floats

    fused_one<<<nmol, 256, 0, stream>>>(frag, Wq, bq, Wk, bk, Wv, bv, midx,
                                        out, Qw, Kw, Vw, ML, n, nmol);
}

// Round 12
// 17.198 us; speedup vs baseline: 1.8576x; 1.1515x over previous
//
#include <hip/hip_runtime.h>
#include <hip/hip_bf16.h>

#define D_MODEL 256
#define D_K 128
#define CH 48           // slow-path staging chunk rows
#define NEG_BF16 ((unsigned short)0xFF7F)   // bf16 -3.39e38; exp() underflows to 0

typedef short bf16x8 __attribute__((ext_vector_type(8)));
typedef float f32x4 __attribute__((ext_vector_type(4)));

__device__ inline unsigned short f2bf(float x) {
    union { float f; unsigned u; } v; v.f = x;
    unsigned r = v.u + 0x7FFFu + ((v.u >> 16) & 1u);  // RNE (finite inputs)
    return (unsigned short)(r >> 16);
}
__device__ inline float bf2f(unsigned short h) {
    union { unsigned u; float f; } v; v.u = ((unsigned)h) << 16; return v.f;
}

// ---- LDS layout (bytes), 512-thread pair blocks. Total 78,848 ----
// At  [64][256] bf16, XOR-swizzled rows      : [0, 32768)
// Vb  [64][136] bf16 (aliases At, post-QKV)  : [0, 17408)
// Qb  [64][136] bf16                         : [32768, 50176)
// Kb  [64][136] bf16                         : [50176, 67584)
// S   [64][68]  bf16                         : [67584, 76288)
// rinv f32[64] (ints s/mid/e during search)  : [76288, 76544)
// csum f32[64]                               : [76544, 76800)
// emb  f32[4][128]                           : [76800, 78848)
#define AT_BYTE(r, c2) (((r) << 9) + ((((c2) << 1)) ^ (((r) & 7) << 4)))
#define QB_OFF 32768
#define KB_OFF 50176
#define S_OFF  67584
#define RINV_OFF 76288
#define CSUM_OFF 76544
#define EMB_OFF  76800

// wave-cooperative lower bound on sorted p: smallest i with p[i] >= val.
__device__ __forceinline__ int wave_lb(const int* __restrict__ p, int stride, int n, int val, int guess) {
    const int lane = threadIdx.x & 63;
    int base = guess - 32;
    while (true) {
        int idx = base + lane;
        int v;
        if (idx < 0)        v = -2147483647 - 1;
        else if (idx >= n)  v = 2147483647;
        else                v = p[(size_t)idx * stride];
        unsigned long long ge = __ballot(v >= val);
        if (ge == 0ULL) { base += 64; continue; }
        int v0 = __shfl(v, 0);
        if (v0 >= val && base > 0) { base -= 63; continue; }
        return base + (__ffsll((unsigned long long)ge) - 1);
    }
}

// B-operand fragment for output column cc at k-window k0 from fp32 W (on-the-fly transpose+convert)
__device__ __forceinline__ bf16x8 w_frag(const float* __restrict__ W, int cc, int k0, int g) {
    const float* p = W + (size_t)(k0 + g * 8) * D_K + cc;
    unsigned short t8[8];
    #pragma unroll
    for (int j = 0; j < 8; ++j) t8[j] = f2bf(p[(size_t)j * D_K]);
    return *(const bf16x8*)t8;
}

// QKV tile pass (8 waves): At(LDS) x W(global fp32) -> acc[3][NRT]; ct = wave + cl*8
template<int NRT>
__device__ __forceinline__ void qkv_tiles(
    const unsigned char* lds,
    const float* __restrict__ Wq, const float* __restrict__ Wk, const float* __restrict__ Wv,
    int wave, int lr, int g, f32x4 (&acc)[3][NRT])
{
    #pragma unroll
    for (int cl = 0; cl < 3; ++cl) {
        const int ct = wave + cl * 8;
        const int which = ct >> 3, cc = (ct & 7) * 16 + lr;
        const float* W = which == 0 ? Wq : (which == 1 ? Wk : Wv);
        #pragma unroll
        for (int k0 = 0; k0 < 8; ++k0) {
            bf16x8 bf = w_frag(W, cc, k0 * 32, g);
            #pragma unroll
            for (int rt = 0; rt < NRT; ++rt) {
                bf16x8 af = *(const bf16x8*)(lds + AT_BYTE(rt * 16 + lr, k0 * 32 + g * 8));
                acc[cl][rt] = __builtin_amdgcn_mfma_f32_16x16x32_bf16(af, bf, acc[cl][rt], 0, 0, 0);
            }
        }
    }
}

// ---------------- pair fast path: rows [s, s+mtot), molecule split at c1 ----------------
// Computes masked softmax over the pair's rows; writes out[mol0] (cols < c1) and out[mol1] (cols >= c1).
template<int NRT>
__device__ __forceinline__ void fast_pair(
    const float* __restrict__ A,
    const float* __restrict__ Wq, const float* __restrict__ bq,
    const float* __restrict__ Wk, const float* __restrict__ bk,
    const float* __restrict__ Wv, const float* __restrict__ bv,
    float* __restrict__ out, unsigned char* lds,
    int s, int mtot, int c1, int mol0, int mol1, bool w0, bool w1)
{
    unsigned short* Qb = (unsigned short*)(lds + QB_OFF);
    unsigned short* Kb = (unsigned short*)(lds + KB_OFF);
    unsigned short* Vb = (unsigned short*)(lds);        // aliases At (after barrier)
    unsigned short* S  = (unsigned short*)(lds + S_OFF);
    float* rinv = (float*)(lds + RINV_OFF);
    float* csum = (float*)(lds + CSUM_OFF);
    float* emb  = (float*)(lds + EMB_OFF);

    const int tid = threadIdx.x;
    const int wave = tid >> 6, lane = tid & 63;
    const int lr = lane & 15, g = lane >> 4;

    // ---- stage A rows -> At bf16 (coalesced; zero-pad to NRT*16 rows) ----
    #pragma unroll
    for (int it = 0; it < NRT * 2; ++it) {   // NRT*16 rows * 256 cols / (512 thr * 4)
        int eidx = tid * 4 + it * 2048;
        int r = eidx >> 8, c = eidx & 255;
        float4 a;
        if (r < mtot) a = *(const float4*)&A[(size_t)(s + r) * D_MODEL + c];
        else          a = make_float4(0.f, 0.f, 0.f, 0.f);
        unsigned short o[4] = {f2bf(a.x), f2bf(a.y), f2bf(a.z), f2bf(a.w)};
        *(unsigned long long*)(lds + AT_BYTE(r, c)) = *(const unsigned long long*)o;
    }
    __syncthreads();

    // ---- QKV MFMA ----
    f32x4 acc[3][NRT];
    #pragma unroll
    for (int i = 0; i < 3; ++i)
        #pragma unroll
        for (int j = 0; j < NRT; ++j) acc[i][j] = {0.f, 0.f, 0.f, 0.f};
    qkv_tiles<NRT>(lds, Wq, Wk, Wv, wave, lr, g, acc);
    __syncthreads();   // At reads done; Vb may overwrite

    // ---- write Q,K,V (+bias, Q scaled) to LDS bf16 ----
    const float qs = 0.08838834764831845f;
    #pragma unroll
    for (int cl = 0; cl < 3; ++cl) {
        int ct = wave + cl * 8;
        int which = ct >> 3;
        int col = (ct & 7) * 16 + lr;
        const float* bsrc = which == 0 ? bq : (which == 1 ? bk : bv);
        float bb = bsrc[col];
        float sc = which == 0 ? qs : 1.f;
        unsigned short* dst = which == 0 ? Qb : (which == 1 ? Kb : Vb);
        #pragma unroll
        for (int rt = 0; rt < NRT; ++rt) {
            int rbase = rt * 16 + g * 4;
            #pragma unroll
            for (int r = 0; r < 4; ++r)
                dst[(rbase + r) * 136 + col] = f2bf((acc[cl][rt][r] + bb) * sc);
        }
    }
    __syncthreads();

    // ---- scores via MFMA with same-molecule mask ----
    for (int job = wave; job < NRT * NRT; job += 8) {
        int ti = job / NRT, tj = job % NRT;
        f32x4 sa = {0.f, 0.f, 0.f, 0.f};
        #pragma unroll
        for (int kk = 0; kk < 4; ++kk) {
            bf16x8 qf = *(const bf16x8*)&Qb[(ti * 16 + lr) * 136 + kk * 32 + g * 8];
            bf16x8 kf = *(const bf16x8*)&Kb[(tj * 16 + lr) * 136 + kk * 32 + g * 8];
            sa = __builtin_amdgcn_mfma_f32_16x16x32_bf16(qf, kf, sa, 0, 0, 0);
        }
        int jcol = tj * 16 + lr, ibase = ti * 16 + g * 4;
        bool jside = jcol < c1;
        #pragma unroll
        for (int r = 0; r < 4; ++r) {
            bool same = ((ibase + r) < c1) == jside;
            S[(ibase + r) * 68 + jcol] = same ? f2bf(sa[r]) : NEG_BF16;
        }
    }
    __syncthreads();

    // ---- row softmax: 4 lanes per row (masked entries exp to 0) ----
    {
        int row = tid >> 2, sub = tid & 3;
        if (row < mtot) {
            float mx = -3.4e38f;
            for (int j = sub; j < mtot; j += 4) mx = fmaxf(mx, bf2f(S[row * 68 + j]));
            mx = fmaxf(mx, __shfl_xor(mx, 1));
            mx = fmaxf(mx, __shfl_xor(mx, 2));
            float sum = 0.f;
            for (int j = sub; j < mtot; j += 4) {
                float ev = __expf(bf2f(S[row * 68 + j]) - mx);
                S[row * 68 + j] = f2bf(ev);
                sum += ev;
            }
            sum += __shfl_xor(sum, 1);
            sum += __shfl_xor(sum, 2);
            if (sub == 0) rinv[row] = 1.f / sum;
        }
    }
    __syncthreads();

    // ---- column sums of normalized weights ----
    {
        int col = tid >> 2, sub = tid & 3;
        if (col < mtot) {
            float a = 0.f;
            for (int i = sub; i < mtot; i += 4) a += bf2f(S[i * 68 + col]) * rinv[i];
            a += __shfl_xor(a, 1);
            a += __shfl_xor(a, 2);
            if (sub == 0) csum[col] = a;
        }
    }
    __syncthreads();

    // ---- V-pool: pass A (j<c1 -> mol0), pass B (j>=c1 -> mol1); 4-way j-split ----
    {
        int d = tid & 127, h = tid >> 7;   // h in 0..3
        float a = 0.f;
        for (int j = h; j < c1; j += 4) a += csum[j] * bf2f(Vb[j * 136 + d]);
        emb[h * D_K + d] = a;
        __syncthreads();
        if (w0 && tid < D_K)
            out[(size_t)mol0 * D_K + tid] = emb[tid] + emb[D_K + tid] + emb[2 * D_K + tid] + emb[3 * D_K + tid];
        __syncthreads();
        a = 0.f;
        for (int j = c1 + h; j < mtot; j += 4) a += csum[j] * bf2f(Vb[j * 136 + d]);
        emb[h * D_K + d] = a;
        __syncthreads();
        if (w1 && tid < D_K)
            out[(size_t)mol1 * D_K + tid] = emb[tid] + emb[D_K + tid] + emb[2 * D_K + tid] + emb[3 * D_K + tid];
    }
}

// dispatch single molecule (m <= 64) through the pair path with an empty second half
__device__ __forceinline__ void run_single(
    const float* __restrict__ A,
    const float* __restrict__ Wq, const float* __restrict__ bq,
    const float* __restrict__ Wk, const float* __restrict__ bk,
    const float* __restrict__ Wv, const float* __restrict__ bv,
    float* __restrict__ out, unsigned char* lds, int s, int m, int mol)
{
    if (m <= 16)      fast_pair<1>(A, Wq, bq, Wk, bk, Wv, bv, out, lds, s, m, m, mol, mol, true, false);
    else if (m <= 32) fast_pair<2>(A, Wq, bq, Wk, bk, Wv, bv, out, lds, s, m, m, mol, mol, true, false);
    else if (m <= 48) fast_pair<3>(A, Wq, bq, Wk, bk, Wv, bv, out, lds, s, m, m, mol, mol, true, false);
    else              fast_pair<4>(A, Wq, bq, Wk, bk, Wv, bv, out, lds, s, m, m, mol, mol, true, false);
}

// streaming slow path for one molecule with m > 64 (statistically never)
__device__ void slow_stream(
    const float* __restrict__ A,
    const float* __restrict__ Wq, const float* __restrict__ bq,
    const float* __restrict__ Wk, const float* __restrict__ bk,
    const float* __restrict__ Wv, const float* __restrict__ bv,
    float* __restrict__ out, unsigned char* lds,
    float* __restrict__ Qw, float* __restrict__ Kw, float* __restrict__ Vw,
    float* __restrict__ ML, int s, int m, int mol, int n)
{
    const int tid = threadIdx.x;
    const int wave = tid >> 6, lane = tid & 63;
    const int lr = lane & 15, g = lane >> 4;
    const float qs = 0.08838834764831845f;
    float* emb = (float*)(lds + EMB_OFF);

    for (int r0 = 0; r0 < m; r0 += CH) {
        for (int it = 0; it < (CH * 256) / 2048; ++it) {   // 6
            int eidx = tid * 4 + it * 2048;
            int r = eidx >> 8, c = eidx & 255;
            float4 a;
            if (r0 + r < m) a = *(const float4*)&A[(size_t)(s + r0 + r) * D_MODEL + c];
            else            a = make_float4(0.f, 0.f, 0.f, 0.f);
            unsigned short o[4] = {f2bf(a.x), f2bf(a.y), f2bf(a.z), f2bf(a.w)};
            *(unsigned long long*)(lds + AT_BYTE(r, c)) = *(const unsigned long long*)o;
        }
        __syncthreads();

        f32x4 acc[3][3];
        #pragma unroll
        for (int i = 0; i < 3; ++i)
            #pragma unroll
            for (int j = 0; j < 3; ++j) acc[i][j] = {0.f, 0.f, 0.f, 0.f};
        qkv_tiles<3>(lds, Wq, Wk, Wv, wave, lr, g, acc);

        #pragma unroll
        for (int cl = 0; cl < 3; ++cl) {
            int ct = wave + cl * 8;
            int which = ct >> 3;
            int col = (ct & 7) * 16 + lr;
            const float* bsrc = which == 0 ? bq : (which == 1 ? bk : bv);
            float bb = bsrc[col];
            float sc = which == 0 ? qs : 1.f;
            float* dst = which == 0 ? Qw : (which == 1 ? Kw : Vw);
            #pragma unroll
            for (int rt = 0; rt < 3; ++rt) {
                int rbase = rt * 16 + g * 4;
                #pragma unroll
                for (int r = 0; r < 4; ++r) {
                    int lrow = rbase + r;
                    if (r0 + lrow < m)
                        dst[(size_t)(s + r0 + lrow) * D_K + col] = (acc[cl][rt][r] + bb) * sc;
                }
            }
        }
        __syncthreads();
    }

    if (tid < D_K) emb[tid] = 0.f;
    float* Mv = ML;
    float* Lv = ML + n;
    __threadfence();
    __syncthreads();

    for (int i = tid; i < m; i += 512) {
        const float4* q = (const float4*)(Qw + (size_t)(s + i) * D_K);
        float mx = -3.4e38f, sum = 0.f;
        for (int j = 0; j < m; ++j) {
            const float4* k = (const float4*)(Kw + (size_t)(s + j) * D_K);
            float sc = 0.f;
            #pragma unroll
            for (int t = 0; t < D_K / 4; ++t) {
                float4 a = q[t], b = k[t];
                sc += a.x * b.x + a.y * b.y + a.z * b.z + a.w * b.w;
            }
            if (sc > mx) { sum = sum * __expf(mx - sc) + 1.f; mx = sc; }
            else         { sum += __expf(sc - mx); }
        }
        Mv[s + i] = mx;
        Lv[s + i] = 1.f / sum;
    }
    __threadfence();
    __syncthreads();

    for (int j = tid; j < m; j += 512) {
        const float4* k = (const float4*)(Kw + (size_t)(s + j) * D_K);
        float cj = 0.f;
        for (int i = 0; i < m; ++i) {
            const float4* q = (const float4*)(Qw + (size_t)(s + i) * D_K);
            float sc = 0.f;
            #pragma unroll
            for (int t = 0; t < D_K / 4; ++t) {
                float4 a = q[t], b = k[t];
                sc += a.x * b.x + a.y * b.y + a.z * b.z + a.w * b.w;
            }
            cj += __expf(sc - Mv[s + i]) * Lv[s + i];
        }
        const float* v = Vw + (size_t)(s + j) * D_K;
        for (int d = 0; d < D_K; ++d) atomicAdd(&emb[d], cj * v[d]);
    }
    __syncthreads();
    if (tid < D_K) out[(size_t)mol * D_K + tid] = emb[tid];
}

// ---------------- single kernel: one block = two consecutive molecules ----------------
__global__ __launch_bounds__(512, 1) void fused_pair(
    const float* __restrict__ A,
    const float* __restrict__ Wq, const float* __restrict__ bq,
    const float* __restrict__ Wk, const float* __restrict__ bk,
    const float* __restrict__ Wv, const float* __restrict__ bv,
    const int* __restrict__ midx,
    float* __restrict__ out,
    float* __restrict__ Qw, float* __restrict__ Kw, float* __restrict__ Vw,
    float* __restrict__ ML, int n, int nmol)
{
    __shared__ __align__(16) unsigned char lds[78848];
    int* se = (int*)(lds + RINV_OFF);   // temp: [0]=s0, [1]=s1, [2]=e

    const int tid = threadIdx.x;
    const int wave = tid >> 6;
    const int mol0 = blockIdx.x * 2;
    const int mol1 = mol0 + 1;
    const bool haveM1 = mol1 < nmol;

    // int64 detection: sorted int64 high words are 0 -> last int32 slot == 0
    const int stride = (midx[n - 1] == 0) ? 2 : 1;

    // ---- segment bounds: waves 0,1,2 search concurrently ----
    if (wave < 3) {
        int val = mol0 + wave;
        if (val > nmol) val = nmol;
        int r = wave_lb(midx, stride, n, val, (int)(((long long)val * n) / nmol));
        if ((tid & 63) == 0) se[wave] = r;
    }
    __syncthreads();
    const int s0 = se[0], s1 = se[1], e = se[2];
    __syncthreads();   // se consumed; rinv area reusable

    const int m0 = s1 - s0, m1 = e - s1, mtot = e - s0;
    const int c1 = m0;

    if (mtot == 0) {
        if (tid < D_K) out[(size_t)mol0 * D_K + tid] = 0.f;
        else if (haveM1 && tid < 2 * D_K) out[(size_t)mol1 * D_K + (tid - D_K)] = 0.f;
        return;
    }

    if (mtot <= 64) {
        if (mtot <= 16)      fast_pair<1>(A, Wq, bq, Wk, bk, Wv, bv, out, lds, s0, mtot, c1, mol0, mol1, true, haveM1);
        else if (mtot <= 32) fast_pair<2>(A, Wq, bq, Wk, bk, Wv, bv, out, lds, s0, mtot, c1, mol0, mol1, true, haveM1);
        else if (mtot <= 48) fast_pair<3>(A, Wq, bq, Wk, bk, Wv, bv, out, lds, s0, mtot, c1, mol0, mol1, true, haveM1);
        else                 fast_pair<4>(A, Wq, bq, Wk, bk, Wv, bv, out, lds, s0, mtot, c1, mol0, mol1, true, haveM1);
        return;
    }

    // ---- rare: pair too large -> per-molecule sequential ----
    if (m0 <= 64) run_single(A, Wq, bq, Wk, bk, Wv, bv, out, lds, s0, m0, mol0);
    else          slow_stream(A, Wq, bq, Wk, bk, Wv, bv, out, lds, Qw, Kw, Vw, ML, s0, m0, mol0, n);
    __syncthreads();
    if (haveM1) {
        if (m1 == 0) { if (tid < D_K) out[(size_t)mol1 * D_K + tid] = 0.f; return; }
        if (m1 <= 64) run_single(A, Wq, bq, Wk, bk, Wv, bv, out, lds, s1, m1, mol1);
        else          slow_stream(A, Wq, bq, Wk, bk, Wv, bv, out, lds, Qw, Kw, Vw, ML, s1, m1, mol1, n);
    }
}

extern "C" void kernel_launch(void* const* d_in, const int* in_sizes, int n_in,
                              void* d_out, int out_size, void* d_ws, size_t ws_size,
                              hipStream_t stream) {
    const float* frag = (const float*)d_in[0];
    const int*   midx = (const int*)d_in[1];
    const float* Wq = (const float*)d_in[2];
    const float* bq = (const float*)d_in[3];
    const float* Wk = (const float*)d_in[4];
    const float* bk = (const float*)d_in[5];
    const float* Wv = (const float*)d_in[6];
    const float* bv = (const float*)d_in[7];
    float* out = (float*)d_out;

    const int n = in_sizes[1];          // 8192
    const int nmol = out_size / D_K;    // 512

    float* Qw = (float*)d_ws;           // slow-path scratch only
    float* Kw = Qw + (size_t)n * D_K;
    float* Vw = Kw + (size_t)n * D_K;
    float* ML = Vw + (size_t)n * D_K;   // 2*n floats

    const int nblocks = (nmol + 1) / 2; // 256
    fused_pair<<<nblocks, 512, 0, stream>>>(frag, Wq, bq, Wk, bk, Wv, bv, midx,
                                            out, Qw, Kw, Vw, ML, n, nmol);
}